// Round 11
// baseline (326.314 us; speedup 1.0000x reference)
//
#include <hip/hip_runtime.h>

#define BLOCK 256
#define WPB (BLOCK / 64)          // 4 waves per block, each owns a 64-edge tile
#define WREG (64 * 19)            // 1216 floats = 4864 B per wave region (76 full lines)

typedef float vf4 __attribute__((ext_vector_type(4)));

// Prepass: pack (pos.xyz, bitcast(batch)) into a 16B-aligned float4 table.
extern "C" __global__ void __launch_bounds__(BLOCK) pack_pos_batch(
    const float* __restrict__ pos,      // [N,3]
    const int*  __restrict__ batch,     // [N]
    vf4* __restrict__ pos4,             // [N] out
    int N)
{
    const int i = blockIdx.x * BLOCK + threadIdx.x;
    if (i < N) {
        vf4 v;
        v.x = pos[3 * i + 0];
        v.y = pos[3 * i + 1];
        v.z = pos[3 * i + 2];
        v.w = __int_as_float(batch[i]);
        pos4[i] = v;
    }
}

template <bool PACKED>
__global__ void __launch_bounds__(BLOCK) edge_encoding_kernel(
    const float* __restrict__ pos,      // [N,3] (fallback)
    const vf4*   __restrict__ pos4,     // [N] packed
    const float* __restrict__ cells,    // [G,3,3] = 144 f32 (G=16)
    const int*   __restrict__ eidx,     // [2,E]
    const int*   __restrict__ pidx,     // [E]
    const int*   __restrict__ batch,    // [N] (fallback)
    float* __restrict__ out,            // [E,19]
    int E)
{
    // (g,p) -> shift vector table: one ds_read_b128 per edge
    __shared__ vf4 s_t[16 * 27];                        // 6912 B
    __shared__ __align__(64) float s_out[WPB * WREG];   // 4 private wave regions

    const int tid = threadIdx.x;
    for (int c = tid; c < 16 * 27; c += BLOCK) {
        const int g = c / 27, p = c % 27;
        const float f0 = (float)(p / 9 - 1);
        const float f1 = (float)((p / 3) % 3 - 1);
        const float f2 = (float)(p % 3 - 1);
        const float* C = cells + g * 9;
        vf4 t;
        t.x = C[0]*f0 + C[3]*f1 + C[6]*f2;
        t.y = C[1]*f0 + C[4]*f1 + C[7]*f2;
        t.z = C[2]*f0 + C[5]*f1 + C[8]*f2;
        t.w = 0.0f;
        s_t[c] = t;
    }
    __syncthreads();   // ONLY barrier in the kernel; nothing in VMEM flight yet

    const int lane = tid & 63;
    const int wid  = tid >> 6;
    const long long e0 = ((long long)blockIdx.x * WPB + wid) * 64;
    if (e0 >= E) return;            // whole-wave exit (after the barrier)

    // ---- per-wave independent dataflow: no further sync of any kind ----
    long long e = e0 + lane;
    if (e >= E) e = E - 1;          // clamped rows never copied out
    const int src = __builtin_nontemporal_load(eidx + e);
    const int dst = __builtin_nontemporal_load(eidx + E + e);
    const int p   = __builtin_nontemporal_load(pidx + e);

    vf4 ps, pd;
    if (PACKED) {
        ps = pos4[src];
        pd = pos4[dst];
    } else {
        ps.x = pos[3*src+0]; ps.y = pos[3*src+1]; ps.z = pos[3*src+2];
        ps.w = __int_as_float(batch[src]);
        pd.x = pos[3*dst+0]; pd.y = pos[3*dst+1]; pd.z = pos[3*dst+2];
        pd.w = 0.0f;
    }

    const float s3  = 1.7320508075688772f;
    const float s5  = 2.2360679774997896f;
    const float s15 = 3.872983346207417f;

    float row[19];
    {
        const int g = __float_as_int(ps.w);
        const vf4 t = s_t[g * 27 + p];

        const float vx = ps.x - pd.x + t.x;
        const float vy = ps.y - pd.y + t.y;
        const float vz = ps.z - pd.z + t.z;

        const float len  = sqrtf(vx*vx + vy*vy + vz*vz);
        const float invl = __builtin_amdgcn_rcpf(fmaxf(len, 1e-6f));
        const float x = vx * invl, y = vy * invl, z = vz * invl;

        row[0] = len;
        row[1] = 1.0f;
        row[2] = s3 * x;
        row[3] = s3 * y;
        row[4] = s3 * z;
        row[5] = s15 * x * z;
        row[6] = s15 * x * y;
        row[7] = s5  * (y*y - 0.5f*(x*x + z*z));
        row[8] = s15 * y * z;
        row[9] = 0.5f * s15 * (z*z - x*x);

        // polynomial cutoff (P=6): 1 - 28 x^6 + 48 x^7 - 21 x^8
        const float xc = fminf(len * (1.0f/6.0f), 1.0f);
        const float x3 = xc * xc * xc;
        const float x6 = x3 * x3;
        const float cut = fmaf(x6, fmaf(xc, fmaf(-21.0f, xc, 48.0f), -28.0f), 1.0f);
        row[10] = cut;

        // bessel via Chebyshev recurrence; native sin/cos (~1e-5 err, tol 0.125)
        const float safe = fminf(fmaxf(len, 1e-6f), 6.0f);
        const float a = safe * 0.5235987755982988f;   // pi/6
        const float sa = __sinf(a);
        const float ca = __cosf(a);
        const float w = cut * 0.5f * __builtin_amdgcn_rcpf(safe);
        const float two_ca = 2.0f * ca;
        float s_prev = 0.0f, s_cur = sa;
        row[11] = s_cur * w;
        #pragma unroll
        for (int n = 2; n <= 8; ++n) {
            const float s_next = two_ca * s_cur - s_prev;
            s_prev = s_cur;
            s_cur  = s_next;
            row[10 + n] = s_cur * w;
        }
    }

    // stage into the wave's PRIVATE region (stride-19: 2 lanes/bank -> free);
    // wave-internal write->read ordering handled by lgkmcnt, no barrier.
    float* s_buf = s_out + wid * WREG;
    #pragma unroll
    for (int j = 0; j < 19; ++j) s_buf[lane * 19 + j] = row[j];

    // copyout: this wave's 64 rows = 4864 B contiguous, 64B-aligned -> full lines
    const int nvalid = (int)(((long long)E - e0) < 64 ? (E - e0) : 64);
    float* gout = out + e0 * 19;
    if (nvalid == 64) {
        const vf4* s4 = reinterpret_cast<const vf4*>(s_buf);
        vf4* g4 = reinterpret_cast<vf4*>(gout);
        #pragma unroll
        for (int i = lane; i < 304; i += 64)    // 304 vf4 = 1216 floats
            g4[i] = s4[i];
    } else {
        const int nf = nvalid * 19;
        for (int i = lane; i < nf; i += 64)
            gout[i] = s_buf[i];
    }
}

extern "C" void kernel_launch(void* const* d_in, const int* in_sizes, int n_in,
                              void* d_out, int out_size, void* d_ws, size_t ws_size,
                              hipStream_t stream) {
    const float* pos   = (const float*)d_in[0];
    const float* cells = (const float*)d_in[1];
    const int*   eidx  = (const int*)d_in[2];
    const int*   pidx  = (const int*)d_in[3];
    const int*   batch = (const int*)d_in[4];
    float* out = (float*)d_out;

    const int E = in_sizes[3];   // periodic_index count = num edges
    const int N = in_sizes[4];   // batch count = num nodes
    const int grid = (int)(((long long)E + BLOCK - 1) / BLOCK);

    if (d_ws != nullptr && ws_size >= (size_t)N * sizeof(vf4)) {
        vf4* pos4 = (vf4*)d_ws;
        const int pgrid = (N + BLOCK - 1) / BLOCK;
        pack_pos_batch<<<pgrid, BLOCK, 0, stream>>>(pos, batch, pos4, N);
        edge_encoding_kernel<true><<<grid, BLOCK, 0, stream>>>(
            pos, pos4, cells, eidx, pidx, batch, out, E);
    } else {
        edge_encoding_kernel<false><<<grid, BLOCK, 0, stream>>>(
            pos, nullptr, cells, eidx, pidx, batch, out, E);
    }
}